// Round 17
// baseline (362.181 us; speedup 1.0000x reference)
//
#include <hip/hip_runtime.h>
#include <hip/hip_bf16.h>
#include <stdint.h>

#define NB   32
#define CIN  256
#define COUT 256
#define WW   56
#define HW   3136
#define NEXP 3
#define KTOT 2304          // 9 * 256
#define XP   58
#define XPP  3364          // 58*58
#define NKT  36            // K-tiles of 64

typedef __attribute__((ext_vector_type(8))) __bf16 bf16x8;
typedef __attribute__((ext_vector_type(4))) float  f32x4;

// workspace layout (bytes)
#define OFF_RW     0
#define OFF_POOLED 1024
#define OFF_CWT    (1024 + 32*256*16*4)
#define CWT_BYTES  ((size_t)NB*COUT*KTOT*2)
#define OFF_XPAD   (OFF_CWT + CWT_BYTES)

// ---------------- fused prologue: xpad + pool + zborder (disjoint ranges) ---
#define PRE_XPAD 6272
#define PRE_POOL 8192
#define PRE_NBLK (PRE_XPAD + PRE_POOL + NB)

__global__ __launch_bounds__(256) void k_pre(const float* __restrict__ x,
                                             float* __restrict__ pooled,
                                             __bf16* __restrict__ xpad) {
    __shared__ __align__(16) char smem[8448];
    int blk = blockIdx.x;
    int t = threadIdx.x;

    if (blk < PRE_XPAD) {
        int pt = blk % 49;
        int r2 = blk / 49;
        int ct = r2 & 3;
        int b  = r2 >> 2;
        __bf16 (*lds)[66] = (__bf16(*)[66])smem;
        int pl = t & 63;
        int cb = t >> 6;
        const float* xb = x + ((size_t)(b * CIN + ct * 64)) * HW + pt * 64;
        #pragma unroll
        for (int ic = 0; ic < 16; ++ic) {
            int cl = ic * 4 + cb;
            lds[cl][pl] = (__bf16)xb[(size_t)cl * HW + pl];
        }
        __syncthreads();
        #pragma unroll
        for (int iw = 0; iw < 2; ++iw) {
            int idx = iw * 256 + t;
            int p_l = idx >> 3, c8 = (idx & 7) * 8;
            int p = pt * 64 + p_l;
            int y = p / WW, xx = p - y * WW;
            union { __bf16 h[8]; uint4 u; } pk;
            #pragma unroll
            for (int j = 0; j < 8; ++j) pk.h[j] = lds[c8 + j][p_l];
            __bf16* dst = xpad + ((size_t)b * XPP + (y + 1) * XP + (xx + 1)) * CIN
                          + ct * 64 + c8;
            *(uint4*)dst = pk.u;
        }
    } else if (blk < PRE_XPAD + PRE_POOL) {
        int j = blk - PRE_XPAD;
        int b = j >> 8, c = j & 255;
        float (*lds)[56] = (float(*)[56])smem;
        const float* xb = x + ((size_t)(b * CIN + c)) * HW;
        if (t < 224) {
            int xc = t % 56, yg = t / 56;
            const float* p = xb + (yg * 14) * WW + xc;
            float s = 0.f;
            #pragma unroll
            for (int r = 0; r < 14; ++r) s += p[r * WW];
            lds[yg][xc] = s;
        }
        __syncthreads();
        if (t < 16) {
            int sy = t >> 2, sx = t & 3;
            float s = 0.f;
            #pragma unroll
            for (int jj = 0; jj < 14; ++jj) s += lds[sy][sx * 14 + jj];
            pooled[(((size_t)b * CIN + c) << 4) + t] = s * (1.f / 196.f);
        }
    } else {
        int b = blk - (PRE_XPAD + PRE_POOL);
        for (int idx = t; idx < 228 * 32; idx += 256) {
            int pos = idx >> 5;
            int co = (idx & 31) * 8;
            int yy, xx;
            if (pos < 58)       { yy = 0;          xx = pos; }
            else if (pos < 116) { yy = 57;         xx = pos - 58; }
            else if (pos < 172) { yy = pos - 115;  xx = 0; }
            else                { yy = pos - 171;  xx = 57; }
            uint4 z = {0u, 0u, 0u, 0u};
            *(uint4*)(xpad + ((size_t)b * XPP + yy * XP + xx) * CIN + co) = z;
        }
    }
}

// ---------------- routing ---------------------------------------------------
__global__ __launch_bounds__(256) void k_route(const float* __restrict__ pooled,
                                               const float* __restrict__ rcw,
                                               const float* __restrict__ rcb,
                                               const float* __restrict__ fcw,
                                               const float* __restrict__ fcb,
                                               float* __restrict__ rw) {
    int b = blockIdx.x;
    int t = threadIdx.x;
    int r = t >> 4, ij = t & 15;
    __shared__ float rbuf[256];
    const float* pb = pooled + (size_t)b * CIN * 16;
    float acc = rcb[r];
    for (int c = 0; c < CIN; ++c)
        acc += pb[c * 16 + ij] * rcw[r * CIN + c];
    rbuf[t] = fmaxf(acc, 0.f);
    __syncthreads();
    if (t < NEXP) {
        float a = fcb[t];
        for (int f = 0; f < 256; ++f) a += rbuf[f] * fcw[t * 256 + f];
        a = fmaxf(a, 0.f);
        rw[b * NEXP + t] = 1.f / (1.f + expf(-a));
    }
}

// ---------------- weight mixing ---------------------------------------------
__global__ __launch_bounds__(256) void k_mixw(const float* __restrict__ we,
                                              const float* __restrict__ rw,
                                              __bf16* __restrict__ cwt) {
    int o = blockIdx.x;
    int i = threadIdx.x;
    float wv[3][9];
    #pragma unroll
    for (int e = 0; e < 3; ++e) {
        const float* p = we + (((size_t)e * COUT + o) * CIN + i) * 9;
        #pragma unroll
        for (int k = 0; k < 9; ++k) wv[e][k] = p[k];
    }
    for (int b = 0; b < NB; ++b) {
        float r0 = rw[b * 3 + 0], r1 = rw[b * 3 + 1], r2 = rw[b * 3 + 2];
        __bf16* op = cwt + ((size_t)(b * COUT + o)) * KTOT + i;
        #pragma unroll
        for (int k = 0; k < 9; ++k) {
            float v = r0 * wv[0][k] + r1 * wv[1][k] + r2 * wv[2][k];
            op[k * 256] = (__bf16)v;
        }
    }
}

// ---------------- implicit-GEMM conv ----------------------------------------
// 256x256 tile, BK=64, 16 waves x 64x64 wave-tiles, **A-only LDS (64 KiB),
// B loaded global->register** (xpad is [pos][ch]: K-innermost, so B-fragments
// are direct 16B global loads; 4 waves share each B-slice -> L1/L2-served).
// Halves LDS traffic (256->128 KB/K-tile) while keeping 16-wave TLP; B rides
// the TA/L1 pipe concurrently with LDS(A) and MFMA pipes.
//
// Phase p = (tile t, half h): issues 4 B-gloads (operands for phase p+1,
// into alternate bq set) + 1 A-stage GL16 (slab (o,h) of tile t+1) + 4
// ds_read af (slab (c,h), published at p-1's barrier); then VMCNT(5)
// retires ALL of phase p-1's 5 VMEM issues (its A-stage -> published by
// this phase's barrier; its B-set -> operand-ready for this phase's MFMA);
// barrier; lgkm0; 16-MFMA cluster.
// RAW(A): slab staged at p, retired at p+1's VMCNT(5), published at p+1's
//   barrier, read at p+2. RAW(B): set loaded at p-1, retired at p's VMCNT.
// WAR(A): slab (o,h) staged at (t,h); its previous reads were at (t-1,h),
//   retired by that wave's LGKM0, 2 barriers earlier.
// Prologue: 4 bqA + 2 A-stages -> VMCNT(1) (retire bqA+A00, keep A01).
// Tail: (35,0) issues 4 bqB only -> VMCNT(4); (35,1) issues none -> VMCNT(0).
#define GL16(g, l) __builtin_amdgcn_global_load_lds( \
    (const __attribute__((address_space(1))) uint32_t*)(g), \
    (__attribute__((address_space(3))) uint32_t*)(l), 16, 0, 0)

#define STAGE_A(o, h, aoffn) \
    GL16(gA + (aoffn) + (h)*64, LDS + (o)*32768 + (h)*16384 + tid*16)

#define BARRIER() do { \
    __builtin_amdgcn_sched_barrier(0); \
    __builtin_amdgcn_s_barrier(); \
    __builtin_amdgcn_sched_barrier(0); \
  } while (0)
#define VMCNT(n) do { \
    asm volatile("s_waitcnt vmcnt(" #n ")" ::: "memory"); \
    __builtin_amdgcn_sched_barrier(0); \
  } while (0)
#define LGKM0() do { \
    asm volatile("s_waitcnt lgkmcnt(0)" ::: "memory"); \
    __builtin_amdgcn_sched_barrier(0); \
  } while (0)

#define LOADA(c, h) do { \
    const char* aCur = LDS + (c)*32768 + (h)*16384 + aRd; \
    af[0] = *(const bf16x8*)(aCur + 0); \
    af[1] = *(const bf16x8*)(aCur + 1024); \
    af[2] = *(const bf16x8*)(aCur + 2048); \
    af[3] = *(const bf16x8*)(aCur + 3072); \
  } while (0)
#define BLOAD(S, boff) do { \
    S[0] = *(const bf16x8*)(bP0 + (boff)); \
    S[1] = *(const bf16x8*)(bP1 + (boff)); \
    S[2] = *(const bf16x8*)(bP2 + (boff)); \
    S[3] = *(const bf16x8*)(bP3 + (boff)); \
  } while (0)
#define MM(S) do { \
    __builtin_amdgcn_s_setprio(1); \
    _Pragma("unroll") \
    for (int mf = 0; mf < 4; ++mf) \
      _Pragma("unroll") \
      for (int nf = 0; nf < 4; ++nf) \
        acc[mf][nf] = __builtin_amdgcn_mfma_f32_16x16x32_bf16( \
            af[mf], S[nf], acc[mf][nf], 0, 0, 0); \
    __builtin_amdgcn_s_setprio(0); \
  } while (0)

__global__ __launch_bounds__(1024, 4) void k_conv(const __bf16* __restrict__ cwt,
                                                  const __bf16* __restrict__ xpad,
                                                  float* __restrict__ out) {
    extern __shared__ __align__(16) char LDS[];

    // XCD swizzle: 416 = 8 * 52 (bijective)
    int flat = blockIdx.x;
    int logical = (flat & 7) * 52 + (flat >> 3);
    int b  = logical / 13;
    int nt = logical - b * 13;

    int tid = threadIdx.x;
    int ln  = tid & 63;
    int wid = tid >> 6;          // 0..15
    int wr  = wid >> 2;          // 0..3: M quarter
    int wc  = wid & 3;           // 0..3: N quarter
    int fr  = ln & 15;
    int kw  = ln >> 4;           // 0..3: 16B k-chunk
    int xsw = ((fr >> 1) & 3) << 4;   // involution within the 64B row

    // ---- A stage source (pre-swizzled global), 1 chunk/thread/slab ----
    const char* gA;
    {
        const char* cwb = (const char*)(cwt + (size_t)b * COUT * KTOT);
        int L = tid * 16;                    // 0..16383
        int U = L ^ (((L >> 7) & 3) << 4);
        int rowU = U >> 6;                   // 0..255
        int kbU  = U & 63;
        gA = cwb + (size_t)rowU * (KTOT * 2) + kbU;
    }
    // ---- B direct-load base pointers (per nf; tile-0,h-0 relative) ----
    const char *bP0, *bP1, *bP2, *bP3;
    {
        const char* xpb = (const char*)(xpad + (size_t)b * XPP * CIN);
        #pragma unroll
        for (int nf = 0; nf < 4; ++nf) {
            int p = nt * 256 + wc * 64 + nf * 16 + fr;
            if (p > HW - 1) p = HW - 1;      // clamp; stores masked
            int y = p / WW, x = p - y * WW;
            const char* bp = xpb + (size_t)(y * XP + x) * (CIN * 2) + kw * 16;
            if (nf == 0) bP0 = bp; else if (nf == 1) bP1 = bp;
            else if (nf == 2) bP2 = bp; else bP3 = bp;
        }
    }

    int aRd = (wr * 64 + fr) * 64 + ((kw * 16) ^ xsw);

    f32x4 acc[4][4];
    #pragma unroll
    for (int i = 0; i < 4; ++i)
        #pragma unroll
        for (int j = 0; j < 4; ++j)
            acc[i][j] = (f32x4){0.f, 0.f, 0.f, 0.f};

    bf16x8 af[4], bqA[4], bqB[4];

    // ---- prologue: bqA(t0,h0); stage A(0,0),(0,1); publish A00 + bqA ----
    BLOAD(bqA, 0);
    STAGE_A(0, 0, 0);
    STAGE_A(0, 1, 0);
    VMCNT(1);
    BARRIER();

    for (int kt = 0; kt < NKT - 1; ++kt) {
        int c = kt & 1, o = c ^ 1;
        int tap  = kt >> 2;
        int ky   = (tap * 11) >> 5;          // tap/3 for 0..8
        int kx   = tap - ky * 3;
        int boff_h1 = (ky * XP + kx) * 512 + (kt & 3) * 128 + 64;
        int ktn  = kt + 1;
        int tapn = ktn >> 2;
        int kyn  = (tapn * 11) >> 5;
        int kxn  = tapn - kyn * 3;
        int boff_n0 = (kyn * XP + kxn) * 512 + (ktn & 3) * 128;
        int aoffn = ktn * 128;

        // ---- phase (kt,0): MFMA uses bqA; load bqB for (kt,1) ----
        BLOAD(bqB, boff_h1);
        STAGE_A(o, 0, aoffn);
        LOADA(c, 0);
        VMCNT(5);
        BARRIER();
        LGKM0();
        MM(bqA);
        // ---- phase (kt,1): MFMA uses bqB; load bqA for (kt+1,0) ----
        BLOAD(bqA, boff_n0);
        STAGE_A(o, 1, aoffn);
        LOADA(c, 1);
        VMCNT(5);
        BARRIER();
        LGKM0();
        MM(bqB);
    }

    // ---- tail tile 35 (buf 1) ----
    {
        // boff(35,1): tap=8 -> ky=2,kx=2; chunk=(35&3)*128; +64
        const int boff_35_1 = (2 * XP + 2) * 512 + 3 * 128 + 64;
        BLOAD(bqB, boff_35_1);
        LOADA(1, 0);
        VMCNT(4);            // retire phase(34,1)'s 5 (A(1,1)-stage + bqA)
        BARRIER();
        LGKM0();
        MM(bqA);
        LOADA(1, 1);
        VMCNT(0);            // retire bqB
        LGKM0();
        MM(bqB);
    }

    // ---- epilogue: col = lane&15, row = (lane>>4)*4 + reg ----
    float* ob = out + ((size_t)(b * COUT + wr * 64)) * HW;
    int colbase = nt * 256 + wc * 64;
    int rb = (ln >> 4) * 4;
    #pragma unroll
    for (int nf = 0; nf < 4; ++nf) {
        int col = colbase + nf * 16 + fr;
        if (col < HW) {
            #pragma unroll
            for (int mf = 0; mf < 4; ++mf)
                #pragma unroll
                for (int r = 0; r < 4; ++r)
                    ob[(size_t)(mf * 16 + rb + r) * HW + col] = acc[mf][nf][r];
        }
    }
}

// ---------------------------------------------------------------------------
extern "C" void kernel_launch(void* const* d_in, const int* in_sizes, int n_in,
                              void* d_out, int out_size, void* d_ws, size_t ws_size,
                              hipStream_t stream) {
    (void)in_sizes; (void)n_in; (void)out_size; (void)ws_size;
    const float* x   = (const float*)d_in[0];
    const float* we  = (const float*)d_in[1];
    const float* rcw = (const float*)d_in[2];
    const float* rcb = (const float*)d_in[3];
    const float* fcw = (const float*)d_in[4];
    const float* fcb = (const float*)d_in[5];
    float* out = (float*)d_out;

    char* ws = (char*)d_ws;
    float*  rw     = (float*)(ws + OFF_RW);
    float*  pooled = (float*)(ws + OFF_POOLED);
    __bf16* cwt    = (__bf16*)(ws + OFF_CWT);
    __bf16* xpad   = (__bf16*)(ws + OFF_XPAD);

    (void)hipFuncSetAttribute((const void*)k_conv,
                              hipFuncAttributeMaxDynamicSharedMemorySize, 65536);

    k_pre<<<PRE_NBLK, 256, 0, stream>>>(x, pooled, xpad);
    k_route<<<NB, 256, 0, stream>>>(pooled, rcw, rcb, fcw, fcb, rw);
    k_mixw<<<COUT, 256, 0, stream>>>(we, rw, cwt);
    k_conv<<<416, 1024, 65536, stream>>>(cwt, xpad, out);
}

// Round 19
// 197.413 us; speedup vs baseline: 1.8346x; 1.8346x over previous
//
#include <hip/hip_runtime.h>
#include <hip/hip_bf16.h>
#include <stdint.h>

#define NB   32
#define CIN  256
#define COUT 256
#define WW   56
#define HW   3136
#define NEXP 3
#define KTOT 2304          // 9 * 256
#define XP   58
#define XPP  3364          // 58*58
#define NKT  36            // K-tiles of 64

typedef __attribute__((ext_vector_type(8))) __bf16 bf16x8;
typedef __attribute__((ext_vector_type(4))) float  f32x4;

// workspace layout (bytes)
#define OFF_RW     0
#define OFF_POOLED 1024
#define OFF_CWT    (1024 + 32*256*16*4)
#define CWT_BYTES  ((size_t)NB*COUT*KTOT*2)
#define OFF_XPAD   (OFF_CWT + CWT_BYTES)

// ---------------- fused prologue: xpad + pool + zborder (disjoint ranges) ---
#define PRE_XPAD 6272
#define PRE_POOL 8192
#define PRE_NBLK (PRE_XPAD + PRE_POOL + NB)

__global__ __launch_bounds__(256) void k_pre(const float* __restrict__ x,
                                             float* __restrict__ pooled,
                                             __bf16* __restrict__ xpad) {
    __shared__ __align__(16) char smem[8448];
    int blk = blockIdx.x;
    int t = threadIdx.x;

    if (blk < PRE_XPAD) {
        int pt = blk % 49;
        int r2 = blk / 49;
        int ct = r2 & 3;
        int b  = r2 >> 2;
        __bf16 (*lds)[66] = (__bf16(*)[66])smem;
        int pl = t & 63;
        int cb = t >> 6;
        const float* xb = x + ((size_t)(b * CIN + ct * 64)) * HW + pt * 64;
        #pragma unroll
        for (int ic = 0; ic < 16; ++ic) {
            int cl = ic * 4 + cb;
            lds[cl][pl] = (__bf16)xb[(size_t)cl * HW + pl];
        }
        __syncthreads();
        #pragma unroll
        for (int iw = 0; iw < 2; ++iw) {
            int idx = iw * 256 + t;
            int p_l = idx >> 3, c8 = (idx & 7) * 8;
            int p = pt * 64 + p_l;
            int y = p / WW, xx = p - y * WW;
            union { __bf16 h[8]; uint4 u; } pk;
            #pragma unroll
            for (int j = 0; j < 8; ++j) pk.h[j] = lds[c8 + j][p_l];
            __bf16* dst = xpad + ((size_t)b * XPP + (y + 1) * XP + (xx + 1)) * CIN
                          + ct * 64 + c8;
            *(uint4*)dst = pk.u;
        }
    } else if (blk < PRE_XPAD + PRE_POOL) {
        int j = blk - PRE_XPAD;
        int b = j >> 8, c = j & 255;
        float (*lds)[56] = (float(*)[56])smem;
        const float* xb = x + ((size_t)(b * CIN + c)) * HW;
        if (t < 224) {
            int xc = t % 56, yg = t / 56;
            const float* p = xb + (yg * 14) * WW + xc;
            float s = 0.f;
            #pragma unroll
            for (int r = 0; r < 14; ++r) s += p[r * WW];
            lds[yg][xc] = s;
        }
        __syncthreads();
        if (t < 16) {
            int sy = t >> 2, sx = t & 3;
            float s = 0.f;
            #pragma unroll
            for (int jj = 0; jj < 14; ++jj) s += lds[sy][sx * 14 + jj];
            pooled[(((size_t)b * CIN + c) << 4) + t] = s * (1.f / 196.f);
        }
    } else {
        int b = blk - (PRE_XPAD + PRE_POOL);
        for (int idx = t; idx < 228 * 32; idx += 256) {
            int pos = idx >> 5;
            int co = (idx & 31) * 8;
            int yy, xx;
            if (pos < 58)       { yy = 0;          xx = pos; }
            else if (pos < 116) { yy = 57;         xx = pos - 58; }
            else if (pos < 172) { yy = pos - 115;  xx = 0; }
            else                { yy = pos - 171;  xx = 57; }
            uint4 z = {0u, 0u, 0u, 0u};
            *(uint4*)(xpad + ((size_t)b * XPP + yy * XP + xx) * CIN + co) = z;
        }
    }
}

// ---------------- routing ---------------------------------------------------
__global__ __launch_bounds__(256) void k_route(const float* __restrict__ pooled,
                                               const float* __restrict__ rcw,
                                               const float* __restrict__ rcb,
                                               const float* __restrict__ fcw,
                                               const float* __restrict__ fcb,
                                               float* __restrict__ rw) {
    int b = blockIdx.x;
    int t = threadIdx.x;
    int r = t >> 4, ij = t & 15;
    __shared__ float rbuf[256];
    const float* pb = pooled + (size_t)b * CIN * 16;
    float acc = rcb[r];
    for (int c = 0; c < CIN; ++c)
        acc += pb[c * 16 + ij] * rcw[r * CIN + c];
    rbuf[t] = fmaxf(acc, 0.f);
    __syncthreads();
    if (t < NEXP) {
        float a = fcb[t];
        for (int f = 0; f < 256; ++f) a += rbuf[f] * fcw[t * 256 + f];
        a = fmaxf(a, 0.f);
        rw[b * NEXP + t] = 1.f / (1.f + expf(-a));
    }
}

// ---------------- weight mixing ---------------------------------------------
__global__ __launch_bounds__(256) void k_mixw(const float* __restrict__ we,
                                              const float* __restrict__ rw,
                                              __bf16* __restrict__ cwt) {
    int o = blockIdx.x;
    int i = threadIdx.x;
    float wv[3][9];
    #pragma unroll
    for (int e = 0; e < 3; ++e) {
        const float* p = we + (((size_t)e * COUT + o) * CIN + i) * 9;
        #pragma unroll
        for (int k = 0; k < 9; ++k) wv[e][k] = p[k];
    }
    for (int b = 0; b < NB; ++b) {
        float r0 = rw[b * 3 + 0], r1 = rw[b * 3 + 1], r2 = rw[b * 3 + 2];
        __bf16* op = cwt + ((size_t)(b * COUT + o)) * KTOT + i;
        #pragma unroll
        for (int k = 0; k < 9; ++k) {
            float v = r0 * wv[0][k] + r1 * wv[1][k] + r2 * wv[2][k];
            op[k * 256] = (__bf16)v;
        }
    }
}

// ---------------- implicit-GEMM conv ----------------------------------------
// 256x256 tile, BK=64, 8 waves x 128x64 wave-tiles, 128 KiB LDS.
// Register-bank software pipeline: phase p's MFMA consumes the fragment bank
// loaded at phase p-1; phase p issues the 12 ds_reads for phase p+1 into the
// alternate bank and waits only lgkmcnt(12) -> LDS service runs CONCURRENTLY
// with the MFMA cluster (R6-R16 serialized them).
// Slab lifecycle (Delta=3): phase p stages the slab consumed at p+3.
// Entry outstanding VMEM = stages from p-1,p-2 (8); VMCNT(4) retires p-2's
// stage = the slab this phase's reads target; the barrier publishes it.
// WAR: slab re-staged 1 barrier after all waves' reads retired (their
// LGKM(12) in the prior phase). Prologue: stage p0,p1,p2 slabs; VMCNT(8).
// Tail: T=34 odd skips stage; tile 35 drains with VMCNT(0).
// NOTE: STAGE_A/B add (kh)*64 internally -> pass boffn WITHOUT the kh term
// (R18 bug: +64 baked into bo1 AND kh=1 -> B kh1 staged from +128).
#define GL16(g, l) __builtin_amdgcn_global_load_lds( \
    (const __attribute__((address_space(1))) uint32_t*)(g), \
    (__attribute__((address_space(3))) uint32_t*)(l), 16, 0, 0)

#define STAGE_A(o, kh, aoffn) do { \
    GL16(gA0 + (aoffn) + (kh)*64, LDS + (o)*32768 + (kh)*16384 + wid*1024); \
    GL16(gA1 + (aoffn) + (kh)*64, LDS + (o)*32768 + (kh)*16384 + 8192 + wid*1024); \
  } while (0)
#define STAGE_B(o, kh, boffn) do { \
    GL16(gB0 + (boffn) + (kh)*64, LDS + 65536 + (o)*32768 + (kh)*16384 + wid*1024); \
    GL16(gB1 + (boffn) + (kh)*64, LDS + 65536 + (o)*32768 + (kh)*16384 + 8192 + wid*1024); \
  } while (0)

#define SB0() __builtin_amdgcn_sched_barrier(0)
#define BARRIER() do { SB0(); __builtin_amdgcn_s_barrier(); SB0(); } while (0)
#define VMCNT(n) do { \
    asm volatile("s_waitcnt vmcnt(" #n ")" ::: "memory"); SB0(); \
  } while (0)
#define LGKM(n) do { \
    asm volatile("s_waitcnt lgkmcnt(" #n ")" ::: "memory"); SB0(); \
  } while (0)

// load one full fragment bank (12 x ds_read_b128) for slab (c,kh)
#define READ12(AF, AG, BQ, c, kh) do { \
    const char* aCur = LDS + (c)*32768 + (kh)*16384 + aRd; \
    const char* bCur = LDS + 65536 + (c)*32768 + (kh)*16384 + bRd; \
    AF[0] = *(const bf16x8*)(aCur + 0); \
    AF[1] = *(const bf16x8*)(aCur + 1024); \
    AF[2] = *(const bf16x8*)(aCur + 2048); \
    AF[3] = *(const bf16x8*)(aCur + 3072); \
    BQ[0] = *(const bf16x8*)(bCur + 0); \
    BQ[1] = *(const bf16x8*)(bCur + 1024); \
    BQ[2] = *(const bf16x8*)(bCur + 2048); \
    BQ[3] = *(const bf16x8*)(bCur + 3072); \
    AG[0] = *(const bf16x8*)(aCur + 4096); \
    AG[1] = *(const bf16x8*)(aCur + 5120); \
    AG[2] = *(const bf16x8*)(aCur + 6144); \
    AG[3] = *(const bf16x8*)(aCur + 7168); \
    SB0(); \
  } while (0)

#define MM32(AF, AG, BQ) do { \
    __builtin_amdgcn_s_setprio(1); \
    _Pragma("unroll") \
    for (int mf = 0; mf < 4; ++mf) \
      _Pragma("unroll") \
      for (int nf = 0; nf < 4; ++nf) \
        acc[mf][nf] = __builtin_amdgcn_mfma_f32_16x16x32_bf16( \
            AF[mf], BQ[nf], acc[mf][nf], 0, 0, 0); \
    _Pragma("unroll") \
    for (int mf = 0; mf < 4; ++mf) \
      _Pragma("unroll") \
      for (int nf = 0; nf < 4; ++nf) \
        acc[4 + mf][nf] = __builtin_amdgcn_mfma_f32_16x16x32_bf16( \
            AG[mf], BQ[nf], acc[4 + mf][nf], 0, 0, 0); \
    __builtin_amdgcn_s_setprio(0); \
  } while (0)

__global__ __launch_bounds__(512, 2) void k_conv(const __bf16* __restrict__ cwt,
                                                 const __bf16* __restrict__ xpad,
                                                 float* __restrict__ out) {
    extern __shared__ __align__(16) char LDS[];

    // XCD swizzle: 416 = 8 * 52 (bijective)
    int flat = blockIdx.x;
    int logical = (flat & 7) * 52 + (flat >> 3);
    int b  = logical / 13;
    int nt = logical - b * 13;

    int tid = threadIdx.x;
    int ln  = tid & 63;
    int wid = tid >> 6;
    int wr  = wid >> 2;
    int wc  = wid & 3;
    int fr  = ln & 15;
    int kw  = ln >> 4;
    int xsw = ((fr >> 1) & 3) << 4;   // involution within the 64B row

    const char *gA0, *gA1, *gB0, *gB1;
    {
        const char* cwb = (const char*)(cwt + (size_t)b * COUT * KTOT);
        const char* xpb = (const char*)(xpad + (size_t)b * XPP * CIN);
        #pragma unroll
        for (int i = 0; i < 2; ++i) {
            int L = i * 8192 + wid * 1024 + ln * 16;
            int U = L ^ (((L >> 7) & 3) << 4);   // same involution as reads
            int rowU = U >> 6;
            int kbU  = U & 63;
            const char* ga = cwb + (size_t)rowU * (KTOT * 2) + kbU;
            int p = nt * 256 + rowU; if (p > HW - 1) p = HW - 1;
            int y = p / WW, x = p - y * WW;
            const char* gb = xpb + (size_t)(y * XP + x) * (CIN * 2) + kbU;
            if (i == 0) { gA0 = ga; gB0 = gb; } else { gA1 = ga; gB1 = gb; }
        }
    }

    int aRd = (wr * 128 + fr) * 64 + ((kw * 16) ^ xsw);
    int bRd = (wc * 64 + fr) * 64 + ((kw * 16) ^ xsw);

    f32x4 acc[8][4];
    #pragma unroll
    for (int i = 0; i < 8; ++i)
        #pragma unroll
        for (int j = 0; j < 4; ++j)
            acc[i][j] = (f32x4){0.f, 0.f, 0.f, 0.f};

    bf16x8 afA[4], agA[4], bqA[4];   // bank 0 (even phases)
    bf16x8 afB[4], agB[4], bqB[4];   // bank 1 (odd phases)

    // ---- prologue: stage slabs for phases 0,1,2; publish phase-0's ----
    STAGE_A(0, 0, 0);  STAGE_B(0, 0, 0);        // (t0,kh0)
    STAGE_A(0, 1, 0);  STAGE_B(0, 1, 0);        // (t0,kh1)
    STAGE_A(1, 0, 128); STAGE_B(1, 0, 128);     // (t1,kh0)
    VMCNT(8);
    BARRIER();
    READ12(afA, agA, bqA, 0, 0);                // bank0 <- (t0,kh0)

    for (int T = 0; T < 35; ++T) {
        int c = T & 1, o = c ^ 1;
        int t1 = T + 1, t2 = T + 2;
        int tap1 = t1 >> 2, ky1 = (tap1 * 11) >> 5, kx1 = tap1 - ky1 * 3;
        int ao1 = t1 * 128;
        int bo1 = (ky1 * XP + kx1) * 512 + (t1 & 3) * 128;  // macro adds kh*64
        int tap2 = t2 >> 2, ky2 = (tap2 * 11) >> 5, kx2 = tap2 - ky2 * 3;
        int ao2 = t2 * 128;
        int bo2 = (ky2 * XP + kx2) * 512 + (t2 & 3) * 128;

        // ---- even phase p=2T: MFMA bank0 (c,kh0); reads -> bank1 (c,kh1) --
        VMCNT(4);
        BARRIER();
        READ12(afB, agB, bqB, c, 1);
        STAGE_A(o, 1, ao1); STAGE_B(o, 1, bo1);     // slab for phase p+3
        LGKM(12);
        MM32(afA, agA, bqA);
        // ---- odd phase p=2T+1: MFMA bank1; reads -> bank0 (t1,kh0) -------
        VMCNT(4);
        BARRIER();
        READ12(afA, agA, bqA, o, 0);
        if (T <= 33) { STAGE_A(c, 0, ao2); STAGE_B(c, 0, bo2); }
        LGKM(12);
        MM32(afB, agB, bqB);
    }

    // ---- tile 35 (buf 1): phases 70, 71 ----
    {
        VMCNT(0);
        BARRIER();
        READ12(afB, agB, bqB, 1, 1);
        LGKM(12);
        MM32(afA, agA, bqA);
        LGKM(0);
        MM32(afB, agB, bqB);
    }

    // ---- epilogue: col = lane&15, row = (lane>>4)*4 + reg ----
    float* ob = out + ((size_t)(b * COUT + wr * 128)) * HW;
    int colbase = nt * 256 + wc * 64;
    int rb = (ln >> 4) * 4;
    #pragma unroll
    for (int q = 0; q < 2; ++q)
        #pragma unroll
        for (int nf = 0; nf < 4; ++nf) {
            int col = colbase + nf * 16 + fr;
            if (col < HW) {
                #pragma unroll
                for (int mf = 0; mf < 4; ++mf)
                    #pragma unroll
                    for (int r = 0; r < 4; ++r)
                        ob[(size_t)(q * 64 + mf * 16 + rb + r) * HW + col] =
                            acc[q * 4 + mf][nf][r];
            }
        }
}

// ---------------------------------------------------------------------------
extern "C" void kernel_launch(void* const* d_in, const int* in_sizes, int n_in,
                              void* d_out, int out_size, void* d_ws, size_t ws_size,
                              hipStream_t stream) {
    (void)in_sizes; (void)n_in; (void)out_size; (void)ws_size;
    const float* x   = (const float*)d_in[0];
    const float* we  = (const float*)d_in[1];
    const float* rcw = (const float*)d_in[2];
    const float* rcb = (const float*)d_in[3];
    const float* fcw = (const float*)d_in[4];
    const float* fcb = (const float*)d_in[5];
    float* out = (float*)d_out;

    char* ws = (char*)d_ws;
    float*  rw     = (float*)(ws + OFF_RW);
    float*  pooled = (float*)(ws + OFF_POOLED);
    __bf16* cwt    = (__bf16*)(ws + OFF_CWT);
    __bf16* xpad   = (__bf16*)(ws + OFF_XPAD);

    (void)hipFuncSetAttribute((const void*)k_conv,
                              hipFuncAttributeMaxDynamicSharedMemorySize, 131072);

    k_pre<<<PRE_NBLK, 256, 0, stream>>>(x, pooled, xpad);
    k_route<<<NB, 256, 0, stream>>>(pooled, rcw, rcb, fcw, fcb, rw);
    k_mixw<<<COUT, 256, 0, stream>>>(we, rw, cwt);
    k_conv<<<416, 512, 131072, stream>>>(cwt, xpad, out);
}

// Round 20
// 194.435 us; speedup vs baseline: 1.8627x; 1.0153x over previous
//
#include <hip/hip_runtime.h>
#include <hip/hip_bf16.h>
#include <stdint.h>

#define NB   32
#define CIN  256
#define COUT 256
#define WW   56
#define HW   3136
#define NEXP 3
#define KTOT 2304          // 9 * 256
#define XP   58
#define XPP  3364          // 58*58
#define NKT  36            // K-tiles of 64

typedef __attribute__((ext_vector_type(8))) __bf16 bf16x8;
typedef __attribute__((ext_vector_type(4))) float  f32x4;

// workspace layout (bytes)
#define OFF_RW     0
#define OFF_POOLED 1024
#define OFF_CWT    (1024 + 32*256*16*4)
#define CWT_BYTES  ((size_t)NB*COUT*KTOT*2)
#define OFF_XPAD   (OFF_CWT + CWT_BYTES)

// ---------------- fused prologue: xpad + pool + zborder (disjoint ranges) ---
#define PRE_XPAD 6272
#define PRE_POOL 8192
#define PRE_NBLK (PRE_XPAD + PRE_POOL + NB)

__global__ __launch_bounds__(256) void k_pre(const float* __restrict__ x,
                                             float* __restrict__ pooled,
                                             __bf16* __restrict__ xpad) {
    __shared__ __align__(16) char smem[8448];
    int blk = blockIdx.x;
    int t = threadIdx.x;

    if (blk < PRE_XPAD) {
        int pt = blk % 49;
        int r2 = blk / 49;
        int ct = r2 & 3;
        int b  = r2 >> 2;
        __bf16 (*lds)[66] = (__bf16(*)[66])smem;
        int pl = t & 63;
        int cb = t >> 6;
        const float* xb = x + ((size_t)(b * CIN + ct * 64)) * HW + pt * 64;
        #pragma unroll
        for (int ic = 0; ic < 16; ++ic) {
            int cl = ic * 4 + cb;
            lds[cl][pl] = (__bf16)xb[(size_t)cl * HW + pl];
        }
        __syncthreads();
        #pragma unroll
        for (int iw = 0; iw < 2; ++iw) {
            int idx = iw * 256 + t;
            int p_l = idx >> 3, c8 = (idx & 7) * 8;
            int p = pt * 64 + p_l;
            int y = p / WW, xx = p - y * WW;
            union { __bf16 h[8]; uint4 u; } pk;
            #pragma unroll
            for (int j = 0; j < 8; ++j) pk.h[j] = lds[c8 + j][p_l];
            __bf16* dst = xpad + ((size_t)b * XPP + (y + 1) * XP + (xx + 1)) * CIN
                          + ct * 64 + c8;
            *(uint4*)dst = pk.u;
        }
    } else if (blk < PRE_XPAD + PRE_POOL) {
        int j = blk - PRE_XPAD;
        int b = j >> 8, c = j & 255;
        float (*lds)[56] = (float(*)[56])smem;
        const float* xb = x + ((size_t)(b * CIN + c)) * HW;
        if (t < 224) {
            int xc = t % 56, yg = t / 56;
            const float* p = xb + (yg * 14) * WW + xc;
            float s = 0.f;
            #pragma unroll
            for (int r = 0; r < 14; ++r) s += p[r * WW];
            lds[yg][xc] = s;
        }
        __syncthreads();
        if (t < 16) {
            int sy = t >> 2, sx = t & 3;
            float s = 0.f;
            #pragma unroll
            for (int jj = 0; jj < 14; ++jj) s += lds[sy][sx * 14 + jj];
            pooled[(((size_t)b * CIN + c) << 4) + t] = s * (1.f / 196.f);
        }
    } else {
        int b = blk - (PRE_XPAD + PRE_POOL);
        for (int idx = t; idx < 228 * 32; idx += 256) {
            int pos = idx >> 5;
            int co = (idx & 31) * 8;
            int yy, xx;
            if (pos < 58)       { yy = 0;          xx = pos; }
            else if (pos < 116) { yy = 57;         xx = pos - 58; }
            else if (pos < 172) { yy = pos - 115;  xx = 0; }
            else                { yy = pos - 171;  xx = 57; }
            uint4 z = {0u, 0u, 0u, 0u};
            *(uint4*)(xpad + ((size_t)b * XPP + yy * XP + xx) * CIN + co) = z;
        }
    }
}

// ---------------- routing ---------------------------------------------------
__global__ __launch_bounds__(256) void k_route(const float* __restrict__ pooled,
                                               const float* __restrict__ rcw,
                                               const float* __restrict__ rcb,
                                               const float* __restrict__ fcw,
                                               const float* __restrict__ fcb,
                                               float* __restrict__ rw) {
    int b = blockIdx.x;
    int t = threadIdx.x;
    int r = t >> 4, ij = t & 15;
    __shared__ float rbuf[256];
    const float* pb = pooled + (size_t)b * CIN * 16;
    float acc = rcb[r];
    for (int c = 0; c < CIN; ++c)
        acc += pb[c * 16 + ij] * rcw[r * CIN + c];
    rbuf[t] = fmaxf(acc, 0.f);
    __syncthreads();
    if (t < NEXP) {
        float a = fcb[t];
        for (int f = 0; f < 256; ++f) a += rbuf[f] * fcw[t * 256 + f];
        a = fmaxf(a, 0.f);
        rw[b * NEXP + t] = 1.f / (1.f + expf(-a));
    }
}

// ---------------- weight mixing ---------------------------------------------
__global__ __launch_bounds__(256) void k_mixw(const float* __restrict__ we,
                                              const float* __restrict__ rw,
                                              __bf16* __restrict__ cwt) {
    int o = blockIdx.x;
    int i = threadIdx.x;
    float wv[3][9];
    #pragma unroll
    for (int e = 0; e < 3; ++e) {
        const float* p = we + (((size_t)e * COUT + o) * CIN + i) * 9;
        #pragma unroll
        for (int k = 0; k < 9; ++k) wv[e][k] = p[k];
    }
    for (int b = 0; b < NB; ++b) {
        float r0 = rw[b * 3 + 0], r1 = rw[b * 3 + 1], r2 = rw[b * 3 + 2];
        __bf16* op = cwt + ((size_t)(b * COUT + o)) * KTOT + i;
        #pragma unroll
        for (int k = 0; k < 9; ++k) {
            float v = r0 * wv[0][k] + r1 * wv[1][k] + r2 * wv[2][k];
            op[k * 256] = (__bf16)v;
        }
    }
}

// ---------------- implicit-GEMM conv ----------------------------------------
// **BM=128 x BN=448 tile** (3136 = 7*448 exactly -> no N masking; grid
// 32*2*7 = 448 blocks -> makespan 2 rounds x 0.875-size blocks = 1.75T vs
// the 256^2 grid's 2.0T). BK=64 (kh-split), 8 waves x 64x112 wave-tiles,
// acc[4][7]. R15 publication-shifted pipeline, re-derived for 5 loads/phase:
//   phase (t,kh) = { 11 ds_reads of slab (c,kh) [published at prev barrier]
//                    -> 5 GL16 stage of slab (t+1,kh) into buf o
//                    -> VMCNT(5) retires the PREVIOUS phase's 5 stages
//                    -> barrier publishes them -> LGKM0 -> 28 MFMA }.
// Outstanding/thread: 5 -> 10 -> VMCNT(5) -> 5. Prologue stages (0,0),(0,1)
// then VMCNT(5)+barrier publishes (0,0). Tail: (35,0) VMCNT(0); (35,1) none.
// WAR: buf o's prior slab (t-1,kh) was read at phase (t-1,kh), retired at
// that wave's LGKM0, 2 barriers before the overwrite-stage at (t,kh).
// LDS (148 KiB): A buf*16384 + kh*8192 ([128 rows][64B], swizzled);
// B 32768 + buf*57344 + kh*28672 ([448 rows][64B], swizzled);
// scrap 147456..151551 (whole-wave dummy B stages land here: B slab = 28 KB
// = 3.5 chunks of 8KB; chunk 3's waves 4..7 map rows 448..511 -> scrap;
// GL16 LDS base is wave-uniform so the redirect is per-wave legal).
#define GL16(g, l) __builtin_amdgcn_global_load_lds( \
    (const __attribute__((address_space(1))) uint32_t*)(g), \
    (__attribute__((address_space(3))) uint32_t*)(l), 16, 0, 0)

#define SB0() __builtin_amdgcn_sched_barrier(0)
#define BARRIER() do { SB0(); __builtin_amdgcn_s_barrier(); SB0(); } while (0)
#define VMCNT(n) do { \
    asm volatile("s_waitcnt vmcnt(" #n ")" ::: "memory"); SB0(); \
  } while (0)
#define LGKM0() do { \
    asm volatile("s_waitcnt lgkmcnt(0)" ::: "memory"); SB0(); \
  } while (0)

// stage slab (t_next, kh) into buf o: 1 A-chunk + 4 B-chunks per thread
#define STAGE(o, kh, aoffn, boffn) do { \
    GL16(gA + (aoffn) + (kh)*64, LDS + (o)*16384 + (kh)*8192 + wid*1024); \
    GL16(gB0 + (boffn) + (kh)*64, \
         LDS + 32768 + (o)*57344 + (kh)*28672 + 0    + wid*1024); \
    GL16(gB1 + (boffn) + (kh)*64, \
         LDS + 32768 + (o)*57344 + (kh)*28672 + 8192 + wid*1024); \
    GL16(gB2 + (boffn) + (kh)*64, \
         LDS + 32768 + (o)*57344 + (kh)*28672 + 16384 + wid*1024); \
    GL16(gB3 + (boffn) + (kh)*64, ldsB3dst + (o)*57344 + (kh)*28672); \
  } while (0)

#define READF(c, kh) do { \
    const char* aCur = LDS + (c)*16384 + (kh)*8192 + aRd; \
    const char* bCur = LDS + 32768 + (c)*57344 + (kh)*28672 + bRd; \
    af[0] = *(const bf16x8*)(aCur + 0); \
    af[1] = *(const bf16x8*)(aCur + 1024); \
    af[2] = *(const bf16x8*)(aCur + 2048); \
    af[3] = *(const bf16x8*)(aCur + 3072); \
    bq[0] = *(const bf16x8*)(bCur + 0); \
    bq[1] = *(const bf16x8*)(bCur + 1024); \
    bq[2] = *(const bf16x8*)(bCur + 2048); \
    bq[3] = *(const bf16x8*)(bCur + 3072); \
    bq[4] = *(const bf16x8*)(bCur + 4096); \
    bq[5] = *(const bf16x8*)(bCur + 5120); \
    bq[6] = *(const bf16x8*)(bCur + 6144); \
    SB0(); \
  } while (0)

#define MM28() do { \
    __builtin_amdgcn_s_setprio(1); \
    _Pragma("unroll") \
    for (int mf = 0; mf < 4; ++mf) \
      _Pragma("unroll") \
      for (int nf = 0; nf < 7; ++nf) \
        acc[mf][nf] = __builtin_amdgcn_mfma_f32_16x16x32_bf16( \
            af[mf], bq[nf], acc[mf][nf], 0, 0, 0); \
    __builtin_amdgcn_s_setprio(0); \
  } while (0)

#define PHASE(c, o, kh, aoffn, boffn) do { \
    READF(c, kh); \
    STAGE(o, kh, aoffn, boffn); \
    VMCNT(5); \
    BARRIER(); \
    LGKM0(); \
    MM28(); \
  } while (0)

__global__ __launch_bounds__(512, 2) void k_conv(const __bf16* __restrict__ cwt,
                                                 const __bf16* __restrict__ xpad,
                                                 float* __restrict__ out) {
    extern __shared__ __align__(16) char LDS[];

    // XCD swizzle: 448 = 8 * 56 (bijective); consecutive logical = same b
    int flat = blockIdx.x;
    int logical = (flat & 7) * 56 + (flat >> 3);
    int b   = logical / 14;
    int rem = logical - b * 14;
    int mtile = rem / 7;
    int ntile = rem - mtile * 7;

    int tid = threadIdx.x;
    int ln  = tid & 63;
    int wid = tid >> 6;          // 0..7
    int wr  = wid >> 2;          // 0..1: M half (rows wr*64..+64)
    int wc  = wid & 3;           // 0..3: N quarter (cols wc*112..+112)
    int fr  = ln & 15;
    int kw  = ln >> 4;           // 0..3: 16B k-chunk
    int xsw = ((fr >> 1) & 3) << 4;   // involution within the 64B row

    // ---- stage source pointers (pre-swizzled global) ----
    const char *gA, *gB0, *gB1, *gB2, *gB3;
    char* ldsB3dst;              // wave-uniform: real rows or scrap
    {
        const char* cwb = (const char*)(cwt + (size_t)b * COUT * KTOT);
        const char* xpb = (const char*)(xpad + (size_t)b * XPP * CIN);
        // A: slab 8 KB, 1 chunk/thread
        {
            int L = tid * 16;                    // 0..8191
            int U = L ^ (((L >> 7) & 3) << 4);
            int rowU = U >> 6;                   // 0..127
            int kbU  = U & 63;
            gA = cwb + (size_t)(mtile * 128 + rowU) * (KTOT * 2) + kbU;
        }
        // B: slab 28 KB, chunks c=0..3 (c=3 rows>=448 -> dummy, whole-wave)
        #pragma unroll
        for (int c = 0; c < 4; ++c) {
            int L = c * 8192 + tid * 16;
            int U = L ^ (((L >> 7) & 3) << 4);
            int rowU = U >> 6;                   // 0..511
            int kbU  = U & 63;
            const char* gb;
            if (rowU < 448) {
                int p = ntile * 448 + rowU;      // always < 3136
                int y = p / WW, x = p - y * WW;
                gb = xpb + (size_t)(y * XP + x) * (CIN * 2) + kbU;
            } else {
                gb = xpb + kbU;                  // dummy, safe
            }
            if (c == 0) gB0 = gb; else if (c == 1) gB1 = gb;
            else if (c == 2) gB2 = gb; else gB3 = gb;
        }
        // chunk-3 LDS dst: waves 0..3 real (rows 384..447), waves 4..7 scrap
        ldsB3dst = (wid < 4)
                 ? (LDS + 32768 + 24576 + wid * 1024)
                 : (LDS + 147456 + (wid - 4) * 1024);
    }

    int aRd = (wr * 64 + fr) * 64 + ((kw * 16) ^ xsw);
    int bRd = (wc * 112 + fr) * 64 + ((kw * 16) ^ xsw);

    f32x4 acc[4][7];
    #pragma unroll
    for (int i = 0; i < 4; ++i)
        #pragma unroll
        for (int j = 0; j < 7; ++j)
            acc[i][j] = (f32x4){0.f, 0.f, 0.f, 0.f};

    bf16x8 af[4], bq[7];

    // ---- prologue: stage (0,0),(0,1); publish (0,0) ----
    STAGE(0, 0, 0, 0);
    STAGE(0, 1, 0, 0);
    VMCNT(5);
    BARRIER();

    for (int kt = 0; kt < NKT - 1; ++kt) {
        int c = kt & 1, o = c ^ 1;
        int ktn  = kt + 1;
        int aoffn = ktn * 128;
        int ktap = ktn >> 2;
        int kyn  = (ktap * 11) >> 5;         // ktap/3 for 0..8
        int kxn  = ktap - kyn * 3;
        int boffn = (kyn * XP + kxn) * 512 + (ktn & 3) * 128;

        PHASE(c, o, 0, aoffn, boffn);
        PHASE(c, o, 1, aoffn, boffn);
    }

    // ---- tail K-tile 35 (buf 1): no stages ----
    {
        // (35,0): entering outstanding = (35,1)'s 5; drain + publish
        READF(1, 0);
        VMCNT(0);
        BARRIER();
        LGKM0();
        MM28();
        // (35,1)
        READF(1, 1);
        LGKM0();
        MM28();
    }

    // ---- epilogue: col = lane&15, row = (lane>>4)*4 + reg; no masking ----
    float* ob = out + ((size_t)(b * COUT + mtile * 128 + wr * 64)) * HW;
    int colbase = ntile * 448 + wc * 112;
    int rb = (ln >> 4) * 4;
    #pragma unroll
    for (int nf = 0; nf < 7; ++nf) {
        int col = colbase + nf * 16 + fr;
        #pragma unroll
        for (int mf = 0; mf < 4; ++mf)
            #pragma unroll
            for (int r = 0; r < 4; ++r)
                ob[(size_t)(mf * 16 + rb + r) * HW + col] = acc[mf][nf][r];
    }
}

// ---------------------------------------------------------------------------
extern "C" void kernel_launch(void* const* d_in, const int* in_sizes, int n_in,
                              void* d_out, int out_size, void* d_ws, size_t ws_size,
                              hipStream_t stream) {
    (void)in_sizes; (void)n_in; (void)out_size; (void)ws_size;
    const float* x   = (const float*)d_in[0];
    const float* we  = (const float*)d_in[1];
    const float* rcw = (const float*)d_in[2];
    const float* rcb = (const float*)d_in[3];
    const float* fcw = (const float*)d_in[4];
    const float* fcb = (const float*)d_in[5];
    float* out = (float*)d_out;

    char* ws = (char*)d_ws;
    float*  rw     = (float*)(ws + OFF_RW);
    float*  pooled = (float*)(ws + OFF_POOLED);
    __bf16* cwt    = (__bf16*)(ws + OFF_CWT);
    __bf16* xpad   = (__bf16*)(ws + OFF_XPAD);

    (void)hipFuncSetAttribute((const void*)k_conv,
                              hipFuncAttributeMaxDynamicSharedMemorySize, 151552);

    k_pre<<<PRE_NBLK, 256, 0, stream>>>(x, pooled, xpad);
    k_route<<<NB, 256, 0, stream>>>(pooled, rcw, rcb, fcw, fcb, rw);
    k_mixw<<<COUT, 256, 0, stream>>>(we, rw, cwt);
    k_conv<<<448, 512, 151552, stream>>>(cwt, xpad, out);
}